// Round 20
// baseline (4475.398 us; speedup 1.0000x reference)
//
#include <hip/hip_runtime.h>
#include <stdint.h>
#include <math.h>

#define D_MODEL 1536
#define NH 12
#define HD 128
#define NL 12
#define SEQ 1024
#define D3 4608
#define D4 6144
#define SCALE 0.025515518153991442f  // 1/sqrt(1536)

typedef __attribute__((ext_vector_type(8))) short short8;
typedef __attribute__((ext_vector_type(4))) float floatx4;

// ---- trunc-based hi/lo split (round-4 semantics, bit-exact)
__device__ __forceinline__ uint32_t packhi(float a, float b) {
  return (__float_as_uint(a) >> 16) | (__float_as_uint(b) & 0xFFFF0000u);
}
__device__ __forceinline__ float truncf32(float a) {
  return __uint_as_float(__float_as_uint(a) & 0xFFFF0000u);
}
__device__ __forceinline__ void split8v(float4 v0, float4 v1, uint4 &hi, uint4 &lo) {
  hi.x = packhi(v0.x, v0.y); hi.y = packhi(v0.z, v0.w);
  hi.z = packhi(v1.x, v1.y); hi.w = packhi(v1.z, v1.w);
  lo.x = packhi(v0.x - truncf32(v0.x), v0.y - truncf32(v0.y));
  lo.y = packhi(v0.z - truncf32(v0.z), v0.w - truncf32(v0.w));
  lo.z = packhi(v1.x - truncf32(v1.x), v1.y - truncf32(v1.y));
  lo.w = packhi(v1.z - truncf32(v1.z), v1.w - truncf32(v1.w));
}

// bijective XCD-chunked block remap (m204)
__device__ __forceinline__ int xcd_chunk_id(int nwg) {
  int orig = blockIdx.x;
  int xcd = orig & 7, pos = orig >> 3;
  int q = nwg >> 3, r = nwg & 7;
  return (xcd < r ? xcd * (q + 1) : r * (q + 1) + (xcd - r) * q) + pos;
}

// ------------------------------------------------------------- embed
__global__ __launch_bounds__(256)
void embed_kernel(const int* __restrict__ idx, const float* __restrict__ tok,
                  const float* __restrict__ pos, float* __restrict__ x) {
  int i = blockIdx.x * 256 + threadIdx.x;
  int s = i / D_MODEL;
  int d = i - s * D_MODEL;
  x[i] = tok[(size_t)idx[s] * D_MODEL + d] + pos[d];  // pos row 0 quirk
}

// ------------------------------------------------------------- hi/lo MFMA GEMM (BM=128 x BN=64, r18-proven)
// TA = number of A planes (1, 2, or 4) summed elementwise at stride APN.
template<bool RELU, bool RES, int SPLITK, int TA>
__global__ __launch_bounds__(256)
void mgemm_kernel(const float* __restrict__ A, size_t APN,
                  const float* __restrict__ B,
                  const float* __restrict__ bias, const float* __restrict__ res,
                  float* __restrict__ C, int M, int N, int K, int NC, int NR) {
  __shared__ short Ah[128][36], Al[128][36];
  __shared__ short Bh[64][36], Bl[64][36];
  const int tid = threadIdx.x;
  const int lane = tid & 63, wave = tid >> 6;

  const int lid = xcd_chunk_id(NC * NR * SPLITK);
  const int z   = lid / (NC * NR);
  const int rem = lid - z * (NC * NR);
  const int ct  = rem / NR;
  const int rt  = rem - ct * NR;
  const int bm = rt << 7, bn = ct << 6;

  const int wm = (wave >> 1) << 6, wn = (wave & 1) << 5;
  const int fr = lane & 15, fk = (lane >> 4) << 3;
  const int Kc = K / SPLITK;
  const int kbase = (SPLITK > 1) ? z * Kc : 0;

  floatx4 acc[4][2];
#pragma unroll
  for (int i = 0; i < 4; i++)
#pragma unroll
    for (int j = 0; j < 2; j++) acc[i][j] = (floatx4){0.f, 0.f, 0.f, 0.f};

  const int ar = tid >> 1;            // A row (128 rows, 2 threads/row)
  const int ac = (tid & 1) << 4;      // 16 floats each
  const int bc = tid & 63;            // B col (64)
  const int bkq = (tid >> 6) << 3;    // k chunk of 8 (0,8,16,24)
  const float* Ag = A + (size_t)(bm + ar) * K + kbase + ac;
  const float* Bg = B + (size_t)(kbase + bkq) * N + bn + bc;

  float a_reg[16];
  float b_reg[8];

  for (int k0 = 0; k0 < Kc; k0 += 32) {
#pragma unroll
    for (int e = 0; e < 4; e++) {
      float4 v = *(const float4*)(Ag + k0 + 4 * e);
      if constexpr (TA >= 2) {
        float4 w = *(const float4*)(Ag + APN + k0 + 4 * e);
        v.x += w.x; v.y += w.y; v.z += w.z; v.w += w.w;
      }
      if constexpr (TA >= 4) {
        float4 u = *(const float4*)(Ag + 2 * APN + k0 + 4 * e);
        float4 t = *(const float4*)(Ag + 3 * APN + k0 + 4 * e);
        v.x += u.x + t.x; v.y += u.y + t.y;
        v.z += u.z + t.z; v.w += u.w + t.w;
      }
      a_reg[4 * e + 0] = v.x; a_reg[4 * e + 1] = v.y;
      a_reg[4 * e + 2] = v.z; a_reg[4 * e + 3] = v.w;
    }
    {
      const float* Bp = Bg + (size_t)k0 * N;
#pragma unroll
      for (int j = 0; j < 8; j++) b_reg[j] = Bp[(size_t)j * N];
    }
    __syncthreads();
#pragma unroll
    for (int e = 0; e < 2; e++) {
      float4 v0 = {a_reg[8 * e + 0], a_reg[8 * e + 1], a_reg[8 * e + 2], a_reg[8 * e + 3]};
      float4 v1 = {a_reg[8 * e + 4], a_reg[8 * e + 5], a_reg[8 * e + 6], a_reg[8 * e + 7]};
      uint4 hi, lo; split8v(v0, v1, hi, lo);
      *(uint4*)&Ah[ar][ac + 8 * e] = hi;
      *(uint4*)&Al[ar][ac + 8 * e] = lo;
    }
    {
      float4 u0 = {b_reg[0], b_reg[1], b_reg[2], b_reg[3]};
      float4 u1 = {b_reg[4], b_reg[5], b_reg[6], b_reg[7]};
      uint4 hi, lo; split8v(u0, u1, hi, lo);
      *(uint4*)&Bh[bc][bkq] = hi;
      *(uint4*)&Bl[bc][bkq] = lo;
    }
    __syncthreads();

    short8 ah[4], al[4], bh[2], bl[2];
#pragma unroll
    for (int i = 0; i < 4; i++) {
      ah[i] = *(const short8*)&Ah[wm + (i << 4) + fr][fk];
      al[i] = *(const short8*)&Al[wm + (i << 4) + fr][fk];
    }
#pragma unroll
    for (int j = 0; j < 2; j++) {
      bh[j] = *(const short8*)&Bh[wn + (j << 4) + fr][fk];
      bl[j] = *(const short8*)&Bl[wn + (j << 4) + fr][fk];
    }
#pragma unroll
    for (int i = 0; i < 4; i++)
#pragma unroll
      for (int j = 0; j < 2; j++) {
        acc[i][j] = __builtin_amdgcn_mfma_f32_16x16x32_bf16(ah[i], bh[j], acc[i][j], 0, 0, 0);
        acc[i][j] = __builtin_amdgcn_mfma_f32_16x16x32_bf16(ah[i], bl[j], acc[i][j], 0, 0, 0);
        acc[i][j] = __builtin_amdgcn_mfma_f32_16x16x32_bf16(al[i], bh[j], acc[i][j], 0, 0, 0);
      }
  }

  const int cr = (lane >> 4) << 2, cc = lane & 15;
  if constexpr (SPLITK > 1) {
    float* Cp = C + (size_t)z * M * N;
#pragma unroll
    for (int j = 0; j < 2; j++) {
      const int col = bn + wn + (j << 4) + cc;
#pragma unroll
      for (int i = 0; i < 4; i++) {
        const int row0 = bm + wm + (i << 4) + cr;
#pragma unroll
        for (int r = 0; r < 4; r++)
          Cp[(size_t)(row0 + r) * N + col] = acc[i][j][r];
      }
    }
  } else {
#pragma unroll
    for (int j = 0; j < 2; j++) {
      const int col = bn + wn + (j << 4) + cc;
      const float bv = bias[col];
#pragma unroll
      for (int i = 0; i < 4; i++) {
        const int row0 = bm + wm + (i << 4) + cr;
#pragma unroll
        for (int r = 0; r < 4; r++) {
          float v = acc[i][j][r] + bv;
          if constexpr (RES) v += res[(size_t)(row0 + r) * N + col];
          if constexpr (RELU) v = fmaxf(v, 0.f);
          C[(size_t)(row0 + r) * N + col] = v;
        }
      }
    }
  }
}

// ------------------------------------------------------------- combineN (split-K merge + epilogue; r14-proven)
template<int NP, bool HASB, bool RES, bool RELU>
__global__ __launch_bounds__(256)
void combineN_kernel(const float* __restrict__ parts, size_t pstride,
                     const float* __restrict__ bias, const float* __restrict__ res,
                     float* __restrict__ C, int N) {
  const int i = (blockIdx.x * 256 + threadIdx.x) << 2;
  float4 r = *(const float4*)&parts[i];
#pragma unroll
  for (int zz = 1; zz < NP; zz++) {
    float4 a = *(const float4*)&parts[(size_t)zz * pstride + i];
    r.x += a.x; r.y += a.y; r.z += a.z; r.w += a.w;
  }
  if constexpr (HASB) {
    const int col = i % N;
    float4 bv = *(const float4*)&bias[col];
    r.x += bv.x; r.y += bv.y; r.z += bv.z; r.w += bv.w;
  }
  if constexpr (RES) {
    float4 rv = *(const float4*)&res[i];
    r.x += rv.x; r.y += rv.y; r.z += rv.z; r.w += rv.w;
  }
  if constexpr (RELU) {
    r.x = fmaxf(r.x, 0.f); r.y = fmaxf(r.y, 0.f);
    r.z = fmaxf(r.z, 0.f); r.w = fmaxf(r.w, 0.f);
  }
  *(float4*)&C[i] = r;
}

// ------------------------------------------------------------- scores (causal tiles, fused col-chunk stats; r13)
__global__ __launch_bounds__(256)
void scores_kernel(const float* __restrict__ qkv, float* __restrict__ scores,
                   float* __restrict__ pstats) {
  __shared__ short Qh[128][40], Ql[128][40], Kh[128][40], Kl[128][40];
  const int tid = threadIdx.x;
  const int lane = tid & 63, wave = tid >> 6;

  const int lid = xcd_chunk_id(NH * 36);
  const int h = lid / 36;
  int t = lid - h * 36;
  int rr = 0;
  while ((rr + 1) * (rr + 2) / 2 <= t) rr++;   // triangular row
  const int bi = rr << 7;
  const int bj = (t - rr * (rr + 1) / 2) << 7;

  const int wm = (wave >> 1) << 6, wn = (wave & 1) << 6;
  const int fr = lane & 15, fk = (lane >> 4) << 3;
  const float* Q = qkv + h * HD;
  const float* Kp = qkv + D_MODEL + h * HD;

  floatx4 acc[4][4];
#pragma unroll
  for (int i = 0; i < 4; i++)
#pragma unroll
    for (int j = 0; j < 4; j++) acc[i][j] = (floatx4){0.f, 0.f, 0.f, 0.f};

  const int ar = tid >> 1;
  const int ac = (tid & 1) << 4;

  for (int k0 = 0; k0 < HD; k0 += 32) {
    __syncthreads();
    {
      const float* Qp = Q + (size_t)(bi + ar) * D3 + k0 + ac;
#pragma unroll
      for (int e = 0; e < 2; e++) {
        float4 v0 = *(const float4*)(Qp + 8 * e);
        float4 v1 = *(const float4*)(Qp + 8 * e + 4);
        uint4 hi, lo; split8v(v0, v1, hi, lo);
        *(uint4*)&Qh[ar][ac + 8 * e] = hi;
        *(uint4*)&Ql[ar][ac + 8 * e] = lo;
      }
      const float* Kpp = Kp + (size_t)(bj + ar) * D3 + k0 + ac;
#pragma unroll
      for (int e = 0; e < 2; e++) {
        float4 v0 = *(const float4*)(Kpp + 8 * e);
        float4 v1 = *(const float4*)(Kpp + 8 * e + 4);
        uint4 hi, lo; split8v(v0, v1, hi, lo);
        *(uint4*)&Kh[ar][ac + 8 * e] = hi;
        *(uint4*)&Kl[ar][ac + 8 * e] = lo;
      }
    }
    __syncthreads();
    short8 qh[4], ql[4], kh[4], kl[4];
#pragma unroll
    for (int i = 0; i < 4; i++) {
      qh[i] = *(const short8*)&Qh[wm + (i << 4) + fr][fk];
      ql[i] = *(const short8*)&Ql[wm + (i << 4) + fr][fk];
      kh[i] = *(const short8*)&Kh[wn + (i << 4) + fr][fk];
      kl[i] = *(const short8*)&Kl[wn + (i << 4) + fr][fk];
    }
#pragma unroll
    for (int i = 0; i < 4; i++)
#pragma unroll
      for (int j = 0; j < 4; j++) {
        acc[i][j] = __builtin_amdgcn_mfma_f32_16x16x32_bf16(qh[i], kh[j], acc[i][j], 0, 0, 0);
        acc[i][j] = __builtin_amdgcn_mfma_f32_16x16x32_bf16(qh[i], kl[j], acc[i][j], 0, 0, 0);
        acc[i][j] = __builtin_amdgcn_mfma_f32_16x16x32_bf16(ql[i], kh[j], acc[i][j], 0, 0, 0);
        acc[i][j] = __builtin_amdgcn_mfma_f32_16x16x32_bf16(ql[i], kl[j], acc[i][j], 0, 0, 0);
      }
  }

  const int cr = (lane >> 4) << 2, cc = lane & 15;
  float* S = scores + (size_t)h * SEQ * SEQ;
  const int qc = (bi >> 6) + (wave >> 1);   // 64-row chunk id (0..15)
  float* Pm = pstats + (size_t)((h * 16 + qc) * 2 + 0) * 1024;
  float* Pz = pstats + (size_t)((h * 16 + qc) * 2 + 1) * 1024;
#pragma unroll
  for (int j = 0; j < 4; j++) {
    const int col = bj + wn + (j << 4) + cc;
    float vv[16];
    float m = -1e30f;
#pragma unroll
    for (int i = 0; i < 4; i++) {
      const int row0 = bi + wm + (i << 4) + cr;
#pragma unroll
      for (int r = 0; r < 4; r++) {
        float v = (col <= row0 + r) ? acc[i][j][r] * SCALE : -1e30f;
        S[(size_t)(row0 + r) * SEQ + col] = v;
        vv[i * 4 + r] = v;
        m = fmaxf(m, v);
      }
    }
    float zz = 0.f;
#pragma unroll
    for (int t2 = 0; t2 < 16; t2++) zz += __expf(vv[t2] - m);
    if (m == -1e30f) zz = 0.f;
#pragma unroll
    for (int off = 16; off <= 32; off <<= 1) {
      float mo = __shfl_xor(m, off, 64);
      float zo = __shfl_xor(zz, off, 64);
      float mn = fmaxf(m, mo);
      zz = zz * __expf(m - mn) + zo * __expf(mo - mn);
      m = mn;
    }
    if ((lane >> 4) == 0) { Pm[col] = m; Pz[col] = zz; }
  }
}

// ------------------------------------------------------------- attn @ V (balanced splitK=4)
// Row-block y has S=2(y+1) 32-steps; chunk z covers steps [zS/4,(z+1)S/4).
__global__ __launch_bounds__(256)
void av_kernel(const float* __restrict__ qkv, const float* __restrict__ scores,
               const float* __restrict__ pstats, float* __restrict__ part) {
  __shared__ short Ph[64][40], Pl[64][40], Vh[128][40], Vl[128][40];
  __shared__ float Ms[512], Rs[512];
  const int tid = threadIdx.x;
  const int lane = tid & 63, wave = tid >> 6;

  const int lid = xcd_chunk_id(NH * 64);     // h*64 + y*4 + z
  const int h = lid >> 6;
  const int t = lid & 63;
  const int y = t >> 2, z = t & 3;
  const int bm = y << 6;

  const int wm = (wave >> 1) << 5, wn = (wave & 1) << 6;
  const int fr = lane & 15, fk = (lane >> 4) << 3;
  const float* S = scores + (size_t)h * SEQ * SEQ;
  const float* V = qkv + 2 * D_MODEL + h * HD;

  const int Ssteps = 2 * (y + 1);
  const int kbeg = ((z * Ssteps) >> 2) * 32;
  const int kend = (((z + 1) * Ssteps) >> 2) * 32;
  const int ncols = kend - kbeg;

  // prologue: merge column stats for [kbeg, kend) (r13 order)
  for (int c0 = tid; c0 < ncols; c0 += 256) {
    const int c = kbeg + c0;
    const int q0 = c >> 6;
    float m = -1e30f;
    for (int qc = q0; qc < 16; qc++)
      m = fmaxf(m, pstats[(size_t)((h * 16 + qc) * 2 + 0) * 1024 + c]);
    float zz = 0.f;
    for (int qc = q0; qc < 16; qc++) {
      float pm = pstats[(size_t)((h * 16 + qc) * 2 + 0) * 1024 + c];
      float pz = pstats[(size_t)((h * 16 + qc) * 2 + 1) * 1024 + c];
      zz += pz * __expf(pm - m);
    }
    Ms[c0] = m;
    Rs[c0] = 1.f / zz;
  }

  floatx4 acc[2][4];
#pragma unroll
  for (int i = 0; i < 2; i++)
#pragma unroll
    for (int j = 0; j < 4; j++) acc[i][j] = (floatx4){0.f, 0.f, 0.f, 0.f};

  const int ar = tid >> 2;
  const int ac = (tid & 3) << 3;
  const int bc = tid & 127;
  const int bkq = (tid >> 7) << 4;

  for (int k0 = kbeg; k0 < kend; k0 += 32) {
    __syncthreads();
    {
      const float* Sp = S + (size_t)(bm + ar) * SEQ + k0 + ac;
      float4 v0 = *(const float4*)(Sp);
      float4 v1 = *(const float4*)(Sp + 4);
      float t8[8] = {v0.x, v0.y, v0.z, v0.w, v1.x, v1.y, v1.z, v1.w};
      float4 p0, p1;
      {
        int kk = k0 - kbeg + ac;
        p0.x = __expf(t8[0] - Ms[kk + 0]) * Rs[kk + 0];
        p0.y = __expf(t8[1] - Ms[kk + 1]) * Rs[kk + 1];
        p0.z = __expf(t8[2] - Ms[kk + 2]) * Rs[kk + 2];
        p0.w = __expf(t8[3] - Ms[kk + 3]) * Rs[kk + 3];
        p1.x = __expf(t8[4] - Ms[kk + 4]) * Rs[kk + 4];
        p1.y = __expf(t8[5] - Ms[kk + 5]) * Rs[kk + 5];
        p1.z = __expf(t8[6] - Ms[kk + 6]) * Rs[kk + 6];
        p1.w = __expf(t8[7] - Ms[kk + 7]) * Rs[kk + 7];
      }
      uint4 hi, lo; split8v(p0, p1, hi, lo);
      *(uint4*)&Ph[ar][ac] = hi;
      *(uint4*)&Pl[ar][ac] = lo;
    }
    {
      const float* Vp = V + (size_t)(k0 + bkq) * D3 + bc;
#pragma unroll
      for (int e = 0; e < 2; e++) {
        float4 u0, u1;
        u0.x = Vp[(size_t)(8 * e + 0) * D3]; u0.y = Vp[(size_t)(8 * e + 1) * D3];
        u0.z = Vp[(size_t)(8 * e + 2) * D3]; u0.w = Vp[(size_t)(8 * e + 3) * D3];
        u1.x = Vp[(size_t)(8 * e + 4) * D3]; u1.y = Vp[(size_t)(8 * e + 5) * D3];
        u1.z = Vp[(size_t)(8 * e + 6) * D3]; u1.w = Vp[(size_t)(8 * e + 7) * D3];
        uint4 hi, lo; split8v(u0, u1, hi, lo);
        *(uint4*)&Vh[bc][bkq + 8 * e] = hi;
        *(uint4*)&Vl[bc][bkq + 8 * e] = lo;
      }
    }
    __syncthreads();
    short8 ph[2], pl[2], vh[4], vl[4];
#pragma unroll
    for (int i = 0; i < 2; i++) {
      ph[i] = *(const short8*)&Ph[wm + (i << 4) + fr][fk];
      pl[i] = *(const short8*)&Pl[wm + (i << 4) + fr][fk];
    }
#pragma unroll
    for (int j = 0; j < 4; j++) {
      vh[j] = *(const short8*)&Vh[wn + (j << 4) + fr][fk];
      vl[j] = *(const short8*)&Vl[wn + (j << 4) + fr][fk];
    }
#pragma unroll
    for (int i = 0; i < 2; i++)
#pragma unroll
      for (int j = 0; j < 4; j++) {
        acc[i][j] = __builtin_amdgcn_mfma_f32_16x16x32_bf16(ph[i], vh[j], acc[i][j], 0, 0, 0);
        acc[i][j] = __builtin_amdgcn_mfma_f32_16x16x32_bf16(ph[i], vl[j], acc[i][j], 0, 0, 0);
        acc[i][j] = __builtin_amdgcn_mfma_f32_16x16x32_bf16(pl[i], vh[j], acc[i][j], 0, 0, 0);
      }
  }

  const int cr = (lane >> 4) << 2, cc = lane & 15;
  float* Cp = part + (size_t)z * SEQ * D_MODEL;
#pragma unroll
  for (int j = 0; j < 4; j++) {
    const int col = h * HD + wn + (j << 4) + cc;
#pragma unroll
    for (int i = 0; i < 2; i++) {
      const int row0 = bm + wm + (i << 4) + cr;
#pragma unroll
      for (int r = 0; r < 4; r++)
        Cp[(size_t)(row0 + r) * D_MODEL + col] = acc[i][j][r];
    }
  }
}

// ------------------------------------------------------------- final LN
__global__ __launch_bounds__(256)
void ln_kernel(const float* __restrict__ x, const float* __restrict__ g,
               const float* __restrict__ bb, float* __restrict__ y) {
  __shared__ float red[8];
  const int row = blockIdx.x;
  const float* xr = x + (size_t)row * D_MODEL;
  float v[6];
  float s = 0.f, sq = 0.f;
#pragma unroll
  for (int i = 0; i < 6; i++) {
    v[i] = xr[256 * i + threadIdx.x];
    s += v[i];
    sq += v[i] * v[i];
  }
#pragma unroll
  for (int off = 32; off >= 1; off >>= 1) {
    s += __shfl_down(s, off, 64);
    sq += __shfl_down(sq, off, 64);
  }
  const int lane = threadIdx.x & 63, w = threadIdx.x >> 6;
  if (lane == 0) { red[w] = s; red[4 + w] = sq; }
  __syncthreads();
  if (threadIdx.x == 0) {
    red[0] = red[0] + red[1] + red[2] + red[3];
    red[4] = red[4] + red[5] + red[6] + red[7];
  }
  __syncthreads();
  const float mu = red[0] * (1.f / D_MODEL);
  const float var = red[4] * (1.f / D_MODEL) - mu * mu;
  const float rs = rsqrtf(var + 1e-5f);
#pragma unroll
  for (int i = 0; i < 6; i++) {
    int c = 256 * i + threadIdx.x;
    y[(size_t)row * D_MODEL + c] = (v[i] - mu) * rs * g[c] + bb[c];
  }
}

// ------------------------------------------------------------- launcher
extern "C" void kernel_launch(void* const* d_in, const int* in_sizes, int n_in,
                              void* d_out, int out_size, void* d_ws, size_t ws_size,
                              hipStream_t stream) {
  (void)in_sizes; (void)n_in; (void)out_size; (void)ws_size;
  const int*   idx     = (const int*)d_in[0];
  const float* tok_emb = (const float*)d_in[2];
  const float* pos_emb = (const float*)d_in[3];
  const float* Wqkv    = (const float*)d_in[4];
  const float* bqkv    = (const float*)d_in[5];
  const float* Wo      = (const float*)d_in[6];
  const float* bo      = (const float*)d_in[7];
  const float* W1      = (const float*)d_in[8];
  const float* b1      = (const float*)d_in[9];
  const float* W2      = (const float*)d_in[10];
  const float* b2      = (const float*)d_in[11];
  const float* ln_g    = (const float*)d_in[12];
  const float* ln_b    = (const float*)d_in[13];
  const float* Wout    = (const float*)d_in[14];
  const float* bout    = (const float*)d_in[15];
  float* out = (float*)d_out;

  char* ws = (char*)d_ws;
  float* x      = (float*)(ws);                 //  6.29 MB
  float* qkv    = (float*)(ws + 6291456);       // 18.87 MB
  float* pstats = (float*)(ws + 25165824);      //  1.57 MB
  float* part   = (float*)(ws + 26836992);      // 50.33 MB (8 planes of SEQ*D_MODEL)
  float* U      = (float*)(ws + 77168640);      // 50.33 MB union {scores|h1|xn}
  float* partC  = (float*)(ws + 127500288);     // 50.33 MB (ffn1 partials, 2 planes)
  float* scores = U;
  float* h1     = U;
  float* xn     = U;
  const size_t PN  = (size_t)SEQ * D_MODEL;
  const size_t PNH = (size_t)SEQ * D4;

  embed_kernel<<<6144, 256, 0, stream>>>(idx, tok_emb, pos_emb, x);

  for (int l = 0; l < NL; l++) {
    const float* wqkv = Wqkv + (size_t)l * D_MODEL * D3;
    const float* bq   = bqkv + (size_t)l * D3;
    const float* wo   = Wo   + (size_t)l * D_MODEL * D_MODEL;
    const float* bo_  = bo   + (size_t)l * D_MODEL;
    const float* w1   = W1   + (size_t)l * D_MODEL * D4;
    const float* b1_  = b1   + (size_t)l * D4;
    const float* w2   = W2   + (size_t)l * D4 * D_MODEL;
    const float* b2_  = b2   + (size_t)l * D_MODEL;

    // qkv = x @ Wqkv + bq   (576 blocks)
    mgemm_kernel<false, false, 1, 1><<<576, 256, 0, stream>>>(
        x, 0, wqkv, bq, nullptr, qkv, SEQ, D3, D_MODEL, 72, 8);
    // attention
    scores_kernel<<<432, 256, 0, stream>>>(qkv, scores, pstats);
    av_kernel<<<768, 256, 0, stream>>>(qkv, scores, pstats, part);   // planes 0-3
    // proj: (av0+av1+av2+av3) @ Wo, splitK=4 -> 768 blocks, planes 4-7
    mgemm_kernel<false, false, 4, 4><<<768, 256, 0, stream>>>(
        part, PN, wo, nullptr, nullptr, part + 4 * PN,
        SEQ, D_MODEL, D_MODEL, 24, 8);
    combineN_kernel<4, true, true, false><<<1536, 256, 0, stream>>>(
        part + 4 * PN, PN, bo_, x, x, D_MODEL);
    // ffn1: x @ W1, splitK=2 -> 1536 blocks; bias+ReLU in combine
    mgemm_kernel<false, false, 2, 1><<<1536, 256, 0, stream>>>(
        x, 0, w1, nullptr, nullptr, partC, SEQ, D4, D_MODEL, 96, 8);
    combineN_kernel<2, true, false, true><<<6144, 256, 0, stream>>>(
        partC, PNH, b1_, nullptr, h1, D4);
    // ffn2: h1 @ W2, splitK=4 -> 768 blocks, planes 0-3
    mgemm_kernel<false, false, 4, 1><<<768, 256, 0, stream>>>(
        h1, 0, w2, nullptr, nullptr, part, SEQ, D_MODEL, D4, 24, 8);
    combineN_kernel<4, true, true, false><<<1536, 256, 0, stream>>>(
        part, PN, b2_, x, x, D_MODEL);
  }

  ln_kernel<<<SEQ, 256, 0, stream>>>(x, ln_g, ln_b, xn);
  mgemm_kernel<false, false, 4, 1><<<768, 256, 0, stream>>>(
      xn, 0, Wout, nullptr, nullptr, part, SEQ, D_MODEL, D_MODEL, 24, 8);
  combineN_kernel<4, true, false, false><<<1536, 256, 0, stream>>>(
      part, PN, bout, nullptr, out, D_MODEL);
}

// Round 21
// 4382.239 us; speedup vs baseline: 1.0213x; 1.0213x over previous
//
#include <hip/hip_runtime.h>
#include <stdint.h>
#include <math.h>

#define D_MODEL 1536
#define NH 12
#define HD 128
#define NL 12
#define SEQ 1024
#define D3 4608
#define D4 6144
#define SCALE 0.025515518153991442f  // 1/sqrt(1536)

typedef __attribute__((ext_vector_type(8))) short short8;
typedef __attribute__((ext_vector_type(4))) float floatx4;

// ---- trunc-based hi/lo split (round-4 semantics, bit-exact)
__device__ __forceinline__ uint32_t packhi(float a, float b) {
  return (__float_as_uint(a) >> 16) | (__float_as_uint(b) & 0xFFFF0000u);
}
__device__ __forceinline__ float truncf32(float a) {
  return __uint_as_float(__float_as_uint(a) & 0xFFFF0000u);
}
__device__ __forceinline__ void split8v(float4 v0, float4 v1, uint4 &hi, uint4 &lo) {
  hi.x = packhi(v0.x, v0.y); hi.y = packhi(v0.z, v0.w);
  hi.z = packhi(v1.x, v1.y); hi.w = packhi(v1.z, v1.w);
  lo.x = packhi(v0.x - truncf32(v0.x), v0.y - truncf32(v0.y));
  lo.y = packhi(v0.z - truncf32(v0.z), v0.w - truncf32(v0.w));
  lo.z = packhi(v1.x - truncf32(v1.x), v1.y - truncf32(v1.y));
  lo.w = packhi(v1.z - truncf32(v1.z), v1.w - truncf32(v1.w));
}

// bijective XCD-chunked block remap (m204)
__device__ __forceinline__ int xcd_chunk_id(int nwg) {
  int orig = blockIdx.x;
  int xcd = orig & 7, pos = orig >> 3;
  int q = nwg >> 3, r = nwg & 7;
  return (xcd < r ? xcd * (q + 1) : r * (q + 1) + (xcd - r) * q) + pos;
}

// ------------------------------------------------------------- embed
__global__ __launch_bounds__(256)
void embed_kernel(const int* __restrict__ idx, const float* __restrict__ tok,
                  const float* __restrict__ pos, float* __restrict__ x) {
  int i = blockIdx.x * 256 + threadIdx.x;
  int s = i / D_MODEL;
  int d = i - s * D_MODEL;
  x[i] = tok[(size_t)idx[s] * D_MODEL + d] + pos[d];  // pos row 0 quirk
}

// ------------------------------------------------------------- hi/lo MFMA GEMM (BM=128 x BN=64, r18-proven)
// TA = number of A planes (1 or 4) summed elementwise at stride APN.
template<bool RELU, bool RES, int SPLITK, int TA>
__global__ __launch_bounds__(256)
void mgemm_kernel(const float* __restrict__ A, size_t APN,
                  const float* __restrict__ B,
                  const float* __restrict__ bias, const float* __restrict__ res,
                  float* __restrict__ C, int M, int N, int K, int NC, int NR) {
  __shared__ short Ah[128][36], Al[128][36];
  __shared__ short Bh[64][36], Bl[64][36];
  const int tid = threadIdx.x;
  const int lane = tid & 63, wave = tid >> 6;

  const int lid = xcd_chunk_id(NC * NR * SPLITK);
  const int z   = lid / (NC * NR);
  const int rem = lid - z * (NC * NR);
  const int ct  = rem / NR;
  const int rt  = rem - ct * NR;
  const int bm = rt << 7, bn = ct << 6;

  const int wm = (wave >> 1) << 6, wn = (wave & 1) << 5;
  const int fr = lane & 15, fk = (lane >> 4) << 3;
  const int Kc = K / SPLITK;
  const int kbase = (SPLITK > 1) ? z * Kc : 0;

  floatx4 acc[4][2];
#pragma unroll
  for (int i = 0; i < 4; i++)
#pragma unroll
    for (int j = 0; j < 2; j++) acc[i][j] = (floatx4){0.f, 0.f, 0.f, 0.f};

  const int ar = tid >> 1;            // A row (128 rows, 2 threads/row)
  const int ac = (tid & 1) << 4;      // 16 floats each
  const int bc = tid & 63;            // B col (64)
  const int bkq = (tid >> 6) << 3;    // k chunk of 8 (0,8,16,24)
  const float* Ag = A + (size_t)(bm + ar) * K + kbase + ac;
  const float* Bg = B + (size_t)(kbase + bkq) * N + bn + bc;

  float a_reg[16];
  float b_reg[8];

  for (int k0 = 0; k0 < Kc; k0 += 32) {
#pragma unroll
    for (int e = 0; e < 4; e++) {
      float4 v = *(const float4*)(Ag + k0 + 4 * e);
      if constexpr (TA >= 2) {
        float4 w = *(const float4*)(Ag + APN + k0 + 4 * e);
        v.x += w.x; v.y += w.y; v.z += w.z; v.w += w.w;
      }
      if constexpr (TA >= 4) {
        float4 u = *(const float4*)(Ag + 2 * APN + k0 + 4 * e);
        float4 t = *(const float4*)(Ag + 3 * APN + k0 + 4 * e);
        v.x += u.x + t.x; v.y += u.y + t.y;
        v.z += u.z + t.z; v.w += u.w + t.w;
      }
      a_reg[4 * e + 0] = v.x; a_reg[4 * e + 1] = v.y;
      a_reg[4 * e + 2] = v.z; a_reg[4 * e + 3] = v.w;
    }
    {
      const float* Bp = Bg + (size_t)k0 * N;
#pragma unroll
      for (int j = 0; j < 8; j++) b_reg[j] = Bp[(size_t)j * N];
    }
    __syncthreads();
#pragma unroll
    for (int e = 0; e < 2; e++) {
      float4 v0 = {a_reg[8 * e + 0], a_reg[8 * e + 1], a_reg[8 * e + 2], a_reg[8 * e + 3]};
      float4 v1 = {a_reg[8 * e + 4], a_reg[8 * e + 5], a_reg[8 * e + 6], a_reg[8 * e + 7]};
      uint4 hi, lo; split8v(v0, v1, hi, lo);
      *(uint4*)&Ah[ar][ac + 8 * e] = hi;
      *(uint4*)&Al[ar][ac + 8 * e] = lo;
    }
    {
      float4 u0 = {b_reg[0], b_reg[1], b_reg[2], b_reg[3]};
      float4 u1 = {b_reg[4], b_reg[5], b_reg[6], b_reg[7]};
      uint4 hi, lo; split8v(u0, u1, hi, lo);
      *(uint4*)&Bh[bc][bkq] = hi;
      *(uint4*)&Bl[bc][bkq] = lo;
    }
    __syncthreads();

    short8 ah[4], al[4], bh[2], bl[2];
#pragma unroll
    for (int i = 0; i < 4; i++) {
      ah[i] = *(const short8*)&Ah[wm + (i << 4) + fr][fk];
      al[i] = *(const short8*)&Al[wm + (i << 4) + fr][fk];
    }
#pragma unroll
    for (int j = 0; j < 2; j++) {
      bh[j] = *(const short8*)&Bh[wn + (j << 4) + fr][fk];
      bl[j] = *(const short8*)&Bl[wn + (j << 4) + fr][fk];
    }
#pragma unroll
    for (int i = 0; i < 4; i++)
#pragma unroll
      for (int j = 0; j < 2; j++) {
        acc[i][j] = __builtin_amdgcn_mfma_f32_16x16x32_bf16(ah[i], bh[j], acc[i][j], 0, 0, 0);
        acc[i][j] = __builtin_amdgcn_mfma_f32_16x16x32_bf16(ah[i], bl[j], acc[i][j], 0, 0, 0);
        acc[i][j] = __builtin_amdgcn_mfma_f32_16x16x32_bf16(al[i], bh[j], acc[i][j], 0, 0, 0);
      }
  }

  const int cr = (lane >> 4) << 2, cc = lane & 15;
  if constexpr (SPLITK > 1) {
    float* Cp = C + (size_t)z * M * N;
#pragma unroll
    for (int j = 0; j < 2; j++) {
      const int col = bn + wn + (j << 4) + cc;
#pragma unroll
      for (int i = 0; i < 4; i++) {
        const int row0 = bm + wm + (i << 4) + cr;
#pragma unroll
        for (int r = 0; r < 4; r++)
          Cp[(size_t)(row0 + r) * N + col] = acc[i][j][r];
      }
    }
  } else {
#pragma unroll
    for (int j = 0; j < 2; j++) {
      const int col = bn + wn + (j << 4) + cc;
      const float bv = bias[col];
#pragma unroll
      for (int i = 0; i < 4; i++) {
        const int row0 = bm + wm + (i << 4) + cr;
#pragma unroll
        for (int r = 0; r < 4; r++) {
          float v = acc[i][j][r] + bv;
          if constexpr (RES) v += res[(size_t)(row0 + r) * N + col];
          if constexpr (RELU) v = fmaxf(v, 0.f);
          C[(size_t)(row0 + r) * N + col] = v;
        }
      }
    }
  }
}

// ------------------------------------------------------------- combineN (split-K merge + epilogue; r14-proven)
template<int NP, bool HASB, bool RES, bool RELU>
__global__ __launch_bounds__(256)
void combineN_kernel(const float* __restrict__ parts, size_t pstride,
                     const float* __restrict__ bias, const float* __restrict__ res,
                     float* __restrict__ C, int N) {
  const int i = (blockIdx.x * 256 + threadIdx.x) << 2;
  float4 r = *(const float4*)&parts[i];
#pragma unroll
  for (int zz = 1; zz < NP; zz++) {
    float4 a = *(const float4*)&parts[(size_t)zz * pstride + i];
    r.x += a.x; r.y += a.y; r.z += a.z; r.w += a.w;
  }
  if constexpr (HASB) {
    const int col = i % N;
    float4 bv = *(const float4*)&bias[col];
    r.x += bv.x; r.y += bv.y; r.z += bv.z; r.w += bv.w;
  }
  if constexpr (RES) {
    float4 rv = *(const float4*)&res[i];
    r.x += rv.x; r.y += rv.y; r.z += rv.z; r.w += rv.w;
  }
  if constexpr (RELU) {
    r.x = fmaxf(r.x, 0.f); r.y = fmaxf(r.y, 0.f);
    r.z = fmaxf(r.z, 0.f); r.w = fmaxf(r.w, 0.f);
  }
  *(float4*)&C[i] = r;
}

// ------------------------------------------------------------- scores (causal tiles, fused col-chunk stats; r13)
__global__ __launch_bounds__(256)
void scores_kernel(const float* __restrict__ qkv, float* __restrict__ scores,
                   float* __restrict__ pstats) {
  __shared__ short Qh[128][40], Ql[128][40], Kh[128][40], Kl[128][40];
  const int tid = threadIdx.x;
  const int lane = tid & 63, wave = tid >> 6;

  const int lid = xcd_chunk_id(NH * 36);
  const int h = lid / 36;
  int t = lid - h * 36;
  int rr = 0;
  while ((rr + 1) * (rr + 2) / 2 <= t) rr++;   // triangular row
  const int bi = rr << 7;
  const int bj = (t - rr * (rr + 1) / 2) << 7;

  const int wm = (wave >> 1) << 6, wn = (wave & 1) << 6;
  const int fr = lane & 15, fk = (lane >> 4) << 3;
  const float* Q = qkv + h * HD;
  const float* Kp = qkv + D_MODEL + h * HD;

  floatx4 acc[4][4];
#pragma unroll
  for (int i = 0; i < 4; i++)
#pragma unroll
    for (int j = 0; j < 4; j++) acc[i][j] = (floatx4){0.f, 0.f, 0.f, 0.f};

  const int ar = tid >> 1;
  const int ac = (tid & 1) << 4;

  for (int k0 = 0; k0 < HD; k0 += 32) {
    __syncthreads();
    {
      const float* Qp = Q + (size_t)(bi + ar) * D3 + k0 + ac;
#pragma unroll
      for (int e = 0; e < 2; e++) {
        float4 v0 = *(const float4*)(Qp + 8 * e);
        float4 v1 = *(const float4*)(Qp + 8 * e + 4);
        uint4 hi, lo; split8v(v0, v1, hi, lo);
        *(uint4*)&Qh[ar][ac + 8 * e] = hi;
        *(uint4*)&Ql[ar][ac + 8 * e] = lo;
      }
      const float* Kpp = Kp + (size_t)(bj + ar) * D3 + k0 + ac;
#pragma unroll
      for (int e = 0; e < 2; e++) {
        float4 v0 = *(const float4*)(Kpp + 8 * e);
        float4 v1 = *(const float4*)(Kpp + 8 * e + 4);
        uint4 hi, lo; split8v(v0, v1, hi, lo);
        *(uint4*)&Kh[ar][ac + 8 * e] = hi;
        *(uint4*)&Kl[ar][ac + 8 * e] = lo;
      }
    }
    __syncthreads();
    short8 qh[4], ql[4], kh[4], kl[4];
#pragma unroll
    for (int i = 0; i < 4; i++) {
      qh[i] = *(const short8*)&Qh[wm + (i << 4) + fr][fk];
      ql[i] = *(const short8*)&Ql[wm + (i << 4) + fr][fk];
      kh[i] = *(const short8*)&Kh[wn + (i << 4) + fr][fk];
      kl[i] = *(const short8*)&Kl[wn + (i << 4) + fr][fk];
    }
#pragma unroll
    for (int i = 0; i < 4; i++)
#pragma unroll
      for (int j = 0; j < 4; j++) {
        acc[i][j] = __builtin_amdgcn_mfma_f32_16x16x32_bf16(qh[i], kh[j], acc[i][j], 0, 0, 0);
        acc[i][j] = __builtin_amdgcn_mfma_f32_16x16x32_bf16(qh[i], kl[j], acc[i][j], 0, 0, 0);
        acc[i][j] = __builtin_amdgcn_mfma_f32_16x16x32_bf16(ql[i], kh[j], acc[i][j], 0, 0, 0);
        acc[i][j] = __builtin_amdgcn_mfma_f32_16x16x32_bf16(ql[i], kl[j], acc[i][j], 0, 0, 0);
      }
  }

  const int cr = (lane >> 4) << 2, cc = lane & 15;
  float* S = scores + (size_t)h * SEQ * SEQ;
  const int qc = (bi >> 6) + (wave >> 1);   // 64-row chunk id (0..15)
  float* Pm = pstats + (size_t)((h * 16 + qc) * 2 + 0) * 1024;
  float* Pz = pstats + (size_t)((h * 16 + qc) * 2 + 1) * 1024;
#pragma unroll
  for (int j = 0; j < 4; j++) {
    const int col = bj + wn + (j << 4) + cc;
    float vv[16];
    float m = -1e30f;
#pragma unroll
    for (int i = 0; i < 4; i++) {
      const int row0 = bi + wm + (i << 4) + cr;
#pragma unroll
      for (int r = 0; r < 4; r++) {
        float v = (col <= row0 + r) ? acc[i][j][r] * SCALE : -1e30f;
        S[(size_t)(row0 + r) * SEQ + col] = v;
        vv[i * 4 + r] = v;
        m = fmaxf(m, v);
      }
    }
    float zz = 0.f;
#pragma unroll
    for (int t2 = 0; t2 < 16; t2++) zz += __expf(vv[t2] - m);
    if (m == -1e30f) zz = 0.f;
#pragma unroll
    for (int off = 16; off <= 32; off <<= 1) {
      float mo = __shfl_xor(m, off, 64);
      float zo = __shfl_xor(zz, off, 64);
      float mn = fmaxf(m, mo);
      zz = zz * __expf(m - mn) + zo * __expf(mo - mn);
      m = mn;
    }
    if ((lane >> 4) == 0) { Pm[col] = m; Pz[col] = zz; }
  }
}

// ------------------------------------------------------------- attn @ V (balanced splitK=4, r20-verified logic)
// Row-block y has S=2(y+1) 32-steps; chunk z covers steps [zS/4,(z+1)S/4).
__global__ __launch_bounds__(256)
void av_kernel(const float* __restrict__ qkv, const float* __restrict__ scores,
               const float* __restrict__ pstats, float* __restrict__ part) {
  __shared__ short Ph[64][40], Pl[64][40], Vh[128][40], Vl[128][40];
  __shared__ float Ms[512], Rs[512];
  const int tid = threadIdx.x;
  const int lane = tid & 63, wave = tid >> 6;

  const int lid = xcd_chunk_id(NH * 64);     // h*64 + y*4 + z
  const int h = lid >> 6;
  const int t = lid & 63;
  const int y = t >> 2, z = t & 3;
  const int bm = y << 6;

  const int wm = (wave >> 1) << 5, wn = (wave & 1) << 6;
  const int fr = lane & 15, fk = (lane >> 4) << 3;
  const float* S = scores + (size_t)h * SEQ * SEQ;
  const float* V = qkv + 2 * D_MODEL + h * HD;

  const int Ssteps = 2 * (y + 1);
  const int kbeg = ((z * Ssteps) >> 2) * 32;
  const int kend = (((z + 1) * Ssteps) >> 2) * 32;
  const int ncols = kend - kbeg;

  for (int c0 = tid; c0 < ncols; c0 += 256) {
    const int c = kbeg + c0;
    const int q0 = c >> 6;
    float m = -1e30f;
    for (int qc = q0; qc < 16; qc++)
      m = fmaxf(m, pstats[(size_t)((h * 16 + qc) * 2 + 0) * 1024 + c]);
    float zz = 0.f;
    for (int qc = q0; qc < 16; qc++) {
      float pm = pstats[(size_t)((h * 16 + qc) * 2 + 0) * 1024 + c];
      float pz = pstats[(size_t)((h * 16 + qc) * 2 + 1) * 1024 + c];
      zz += pz * __expf(pm - m);
    }
    Ms[c0] = m;
    Rs[c0] = 1.f / zz;
  }

  floatx4 acc[2][4];
#pragma unroll
  for (int i = 0; i < 2; i++)
#pragma unroll
    for (int j = 0; j < 4; j++) acc[i][j] = (floatx4){0.f, 0.f, 0.f, 0.f};

  const int ar = tid >> 2;
  const int ac = (tid & 3) << 3;
  const int bc = tid & 127;
  const int bkq = (tid >> 7) << 4;

  for (int k0 = kbeg; k0 < kend; k0 += 32) {
    __syncthreads();
    {
      const float* Sp = S + (size_t)(bm + ar) * SEQ + k0 + ac;
      float4 v0 = *(const float4*)(Sp);
      float4 v1 = *(const float4*)(Sp + 4);
      float t8[8] = {v0.x, v0.y, v0.z, v0.w, v1.x, v1.y, v1.z, v1.w};
      float4 p0, p1;
      {
        int kk = k0 - kbeg + ac;
        p0.x = __expf(t8[0] - Ms[kk + 0]) * Rs[kk + 0];
        p0.y = __expf(t8[1] - Ms[kk + 1]) * Rs[kk + 1];
        p0.z = __expf(t8[2] - Ms[kk + 2]) * Rs[kk + 2];
        p0.w = __expf(t8[3] - Ms[kk + 3]) * Rs[kk + 3];
        p1.x = __expf(t8[4] - Ms[kk + 4]) * Rs[kk + 4];
        p1.y = __expf(t8[5] - Ms[kk + 5]) * Rs[kk + 5];
        p1.z = __expf(t8[6] - Ms[kk + 6]) * Rs[kk + 6];
        p1.w = __expf(t8[7] - Ms[kk + 7]) * Rs[kk + 7];
      }
      uint4 hi, lo; split8v(p0, p1, hi, lo);
      *(uint4*)&Ph[ar][ac] = hi;
      *(uint4*)&Pl[ar][ac] = lo;
    }
    {
      const float* Vp = V + (size_t)(k0 + bkq) * D3 + bc;
#pragma unroll
      for (int e = 0; e < 2; e++) {
        float4 u0, u1;
        u0.x = Vp[(size_t)(8 * e + 0) * D3]; u0.y = Vp[(size_t)(8 * e + 1) * D3];
        u0.z = Vp[(size_t)(8 * e + 2) * D3]; u0.w = Vp[(size_t)(8 * e + 3) * D3];
        u1.x = Vp[(size_t)(8 * e + 4) * D3]; u1.y = Vp[(size_t)(8 * e + 5) * D3];
        u1.z = Vp[(size_t)(8 * e + 6) * D3]; u1.w = Vp[(size_t)(8 * e + 7) * D3];
        uint4 hi, lo; split8v(u0, u1, hi, lo);
        *(uint4*)&Vh[bc][bkq + 8 * e] = hi;
        *(uint4*)&Vl[bc][bkq + 8 * e] = lo;
      }
    }
    __syncthreads();
    short8 ph[2], pl[2], vh[4], vl[4];
#pragma unroll
    for (int i = 0; i < 2; i++) {
      ph[i] = *(const short8*)&Ph[wm + (i << 4) + fr][fk];
      pl[i] = *(const short8*)&Pl[wm + (i << 4) + fr][fk];
    }
#pragma unroll
    for (int j = 0; j < 4; j++) {
      vh[j] = *(const short8*)&Vh[wn + (j << 4) + fr][fk];
      vl[j] = *(const short8*)&Vl[wn + (j << 4) + fr][fk];
    }
#pragma unroll
    for (int i = 0; i < 2; i++)
#pragma unroll
      for (int j = 0; j < 4; j++) {
        acc[i][j] = __builtin_amdgcn_mfma_f32_16x16x32_bf16(ph[i], vh[j], acc[i][j], 0, 0, 0);
        acc[i][j] = __builtin_amdgcn_mfma_f32_16x16x32_bf16(ph[i], vl[j], acc[i][j], 0, 0, 0);
        acc[i][j] = __builtin_amdgcn_mfma_f32_16x16x32_bf16(pl[i], vh[j], acc[i][j], 0, 0, 0);
      }
  }

  const int cr = (lane >> 4) << 2, cc = lane & 15;
  float* Cp = part + (size_t)z * SEQ * D_MODEL;
#pragma unroll
  for (int j = 0; j < 4; j++) {
    const int col = h * HD + wn + (j << 4) + cc;
#pragma unroll
    for (int i = 0; i < 2; i++) {
      const int row0 = bm + wm + (i << 4) + cr;
#pragma unroll
      for (int r = 0; r < 4; r++)
        Cp[(size_t)(row0 + r) * D_MODEL + col] = acc[i][j][r];
    }
  }
}

// ------------------------------------------------------------- final LN
__global__ __launch_bounds__(256)
void ln_kernel(const float* __restrict__ x, const float* __restrict__ g,
               const float* __restrict__ bb, float* __restrict__ y) {
  __shared__ float red[8];
  const int row = blockIdx.x;
  const float* xr = x + (size_t)row * D_MODEL;
  float v[6];
  float s = 0.f, sq = 0.f;
#pragma unroll
  for (int i = 0; i < 6; i++) {
    v[i] = xr[256 * i + threadIdx.x];
    s += v[i];
    sq += v[i] * v[i];
  }
#pragma unroll
  for (int off = 32; off >= 1; off >>= 1) {
    s += __shfl_down(s, off, 64);
    sq += __shfl_down(sq, off, 64);
  }
  const int lane = threadIdx.x & 63, w = threadIdx.x >> 6;
  if (lane == 0) { red[w] = s; red[4 + w] = sq; }
  __syncthreads();
  if (threadIdx.x == 0) {
    red[0] = red[0] + red[1] + red[2] + red[3];
    red[4] = red[4] + red[5] + red[6] + red[7];
  }
  __syncthreads();
  const float mu = red[0] * (1.f / D_MODEL);
  const float var = red[4] * (1.f / D_MODEL) - mu * mu;
  const float rs = rsqrtf(var + 1e-5f);
#pragma unroll
  for (int i = 0; i < 6; i++) {
    int c = 256 * i + threadIdx.x;
    y[(size_t)row * D_MODEL + c] = (v[i] - mu) * rs * g[c] + bb[c];
  }
}

// ------------------------------------------------------------- launcher
extern "C" void kernel_launch(void* const* d_in, const int* in_sizes, int n_in,
                              void* d_out, int out_size, void* d_ws, size_t ws_size,
                              hipStream_t stream) {
  (void)in_sizes; (void)n_in; (void)out_size; (void)ws_size;
  const int*   idx     = (const int*)d_in[0];
  const float* tok_emb = (const float*)d_in[2];
  const float* pos_emb = (const float*)d_in[3];
  const float* Wqkv    = (const float*)d_in[4];
  const float* bqkv    = (const float*)d_in[5];
  const float* Wo      = (const float*)d_in[6];
  const float* bo      = (const float*)d_in[7];
  const float* W1      = (const float*)d_in[8];
  const float* b1      = (const float*)d_in[9];
  const float* W2      = (const float*)d_in[10];
  const float* b2      = (const float*)d_in[11];
  const float* ln_g    = (const float*)d_in[12];
  const float* ln_b    = (const float*)d_in[13];
  const float* Wout    = (const float*)d_in[14];
  const float* bout    = (const float*)d_in[15];
  float* out = (float*)d_out;

  char* ws = (char*)d_ws;
  float* x      = (float*)(ws);                 //  6.29 MB
  float* qkv    = (float*)(ws + 6291456);       // 18.87 MB
  float* pstats = (float*)(ws + 25165824);      //  1.57 MB
  float* part   = (float*)(ws + 26836992);      // 50.33 MB (8 planes of SEQ*D_MODEL)
  float* U      = (float*)(ws + 77168640);      // 50.33 MB union {scores|h1|xn}
  float* scores = U;
  float* h1     = U;
  float* xn     = U;
  const size_t PN = (size_t)SEQ * D_MODEL;

  embed_kernel<<<6144, 256, 0, stream>>>(idx, tok_emb, pos_emb, x);

  for (int l = 0; l < NL; l++) {
    const float* wqkv = Wqkv + (size_t)l * D_MODEL * D3;
    const float* bq   = bqkv + (size_t)l * D3;
    const float* wo   = Wo   + (size_t)l * D_MODEL * D_MODEL;
    const float* bo_  = bo   + (size_t)l * D_MODEL;
    const float* w1   = W1   + (size_t)l * D_MODEL * D4;
    const float* b1_  = b1   + (size_t)l * D4;
    const float* w2   = W2   + (size_t)l * D4 * D_MODEL;
    const float* b2_  = b2   + (size_t)l * D_MODEL;

    // qkv = x @ Wqkv + bq   (576 blocks; r19)
    mgemm_kernel<false, false, 1, 1><<<576, 256, 0, stream>>>(
        x, 0, wqkv, bq, nullptr, qkv, SEQ, D3, D_MODEL, 72, 8);
    // attention
    scores_kernel<<<432, 256, 0, stream>>>(qkv, scores, pstats);
    av_kernel<<<768, 256, 0, stream>>>(qkv, scores, pstats, part);   // planes 0-3
    // proj: (av0..av3) @ Wo, splitK=4 -> 768 blocks, planes 4-7
    mgemm_kernel<false, false, 4, 4><<<768, 256, 0, stream>>>(
        part, PN, wo, nullptr, nullptr, part + 4 * PN,
        SEQ, D_MODEL, D_MODEL, 24, 8);
    combineN_kernel<4, true, true, false><<<1536, 256, 0, stream>>>(
        part + 4 * PN, PN, bo_, x, x, D_MODEL);
    // h1 = relu(x @ W1 + b1)   (768 blocks, fused epilogue; r19)
    mgemm_kernel<true, false, 1, 1><<<768, 256, 0, stream>>>(
        x, 0, w1, b1_, nullptr, h1, SEQ, D4, D_MODEL, 96, 8);
    // ffn2: h1 @ W2, splitK=4 -> 768 blocks, planes 0-3 (r19)
    mgemm_kernel<false, false, 4, 1><<<768, 256, 0, stream>>>(
        h1, 0, w2, nullptr, nullptr, part, SEQ, D_MODEL, D4, 24, 8);
    combineN_kernel<4, true, true, false><<<1536, 256, 0, stream>>>(
        part, PN, b2_, x, x, D_MODEL);
  }

  ln_kernel<<<SEQ, 256, 0, stream>>>(x, ln_g, ln_b, xn);
  mgemm_kernel<false, false, 4, 1><<<768, 256, 0, stream>>>(
      xn, 0, Wout, nullptr, nullptr, part, SEQ, D_MODEL, D_MODEL, 24, 8);
  combineN_kernel<4, true, false, false><<<1536, 256, 0, stream>>>(
      part, PN, bout, nullptr, out, D_MODEL);
}

// Round 22
// 4251.540 us; speedup vs baseline: 1.0527x; 1.0307x over previous
//
#include <hip/hip_runtime.h>
#include <stdint.h>
#include <math.h>

#define D_MODEL 1536
#define NH 12
#define HD 128
#define NL 12
#define SEQ 1024
#define D3 4608
#define D4 6144
#define SCALE 0.025515518153991442f  // 1/sqrt(1536)

typedef __attribute__((ext_vector_type(8))) short short8;
typedef __attribute__((ext_vector_type(4))) float floatx4;

// ---- trunc-based hi/lo split (round-4 semantics, bit-exact)
__device__ __forceinline__ uint32_t packhi(float a, float b) {
  return (__float_as_uint(a) >> 16) | (__float_as_uint(b) & 0xFFFF0000u);
}
__device__ __forceinline__ float truncf32(float a) {
  return __uint_as_float(__float_as_uint(a) & 0xFFFF0000u);
}
__device__ __forceinline__ void split8v(float4 v0, float4 v1, uint4 &hi, uint4 &lo) {
  hi.x = packhi(v0.x, v0.y); hi.y = packhi(v0.z, v0.w);
  hi.z = packhi(v1.x, v1.y); hi.w = packhi(v1.z, v1.w);
  lo.x = packhi(v0.x - truncf32(v0.x), v0.y - truncf32(v0.y));
  lo.y = packhi(v0.z - truncf32(v0.z), v0.w - truncf32(v0.w));
  lo.z = packhi(v1.x - truncf32(v1.x), v1.y - truncf32(v1.y));
  lo.w = packhi(v1.z - truncf32(v1.z), v1.w - truncf32(v1.w));
}

// bijective XCD-chunked block remap (m204)
__device__ __forceinline__ int xcd_chunk_id(int nwg) {
  int orig = blockIdx.x;
  int xcd = orig & 7, pos = orig >> 3;
  int q = nwg >> 3, r = nwg & 7;
  return (xcd < r ? xcd * (q + 1) : r * (q + 1) + (xcd - r) * q) + pos;
}

// ------------------------------------------------------------- embed
__global__ __launch_bounds__(256)
void embed_kernel(const int* __restrict__ idx, const float* __restrict__ tok,
                  const float* __restrict__ pos, float* __restrict__ x) {
  int i = blockIdx.x * 256 + threadIdx.x;
  int s = i / D_MODEL;
  int d = i - s * D_MODEL;
  x[i] = tok[(size_t)idx[s] * D_MODEL + d] + pos[d];  // pos row 0 quirk
}

// ------------------------------------------------------------- hi/lo MFMA GEMM (BM=128 x BN=64, r18-proven)
template<bool RELU, bool RES, int SPLITK, bool TA2>
__global__ __launch_bounds__(256)
void mgemm_kernel(const float* __restrict__ A, const float* __restrict__ Ab,
                  const float* __restrict__ B,
                  const float* __restrict__ bias, const float* __restrict__ res,
                  float* __restrict__ C, int M, int N, int K, int NC, int NR) {
  __shared__ short Ah[128][36], Al[128][36];
  __shared__ short Bh[64][36], Bl[64][36];
  const int tid = threadIdx.x;
  const int lane = tid & 63, wave = tid >> 6;

  const int lid = xcd_chunk_id(NC * NR * SPLITK);
  const int z   = lid / (NC * NR);
  const int rem = lid - z * (NC * NR);
  const int ct  = rem / NR;
  const int rt  = rem - ct * NR;
  const int bm = rt << 7, bn = ct << 6;

  const int wm = (wave >> 1) << 6, wn = (wave & 1) << 5;
  const int fr = lane & 15, fk = (lane >> 4) << 3;
  const int Kc = K / SPLITK;
  const int kbase = (SPLITK > 1) ? z * Kc : 0;

  floatx4 acc[4][2];
#pragma unroll
  for (int i = 0; i < 4; i++)
#pragma unroll
    for (int j = 0; j < 2; j++) acc[i][j] = (floatx4){0.f, 0.f, 0.f, 0.f};

  const int ar = tid >> 1;            // A row (128 rows, 2 threads/row)
  const int ac = (tid & 1) << 4;      // 16 floats each
  const int bc = tid & 63;            // B col (64)
  const int bkq = (tid >> 6) << 3;    // k chunk of 8 (0,8,16,24)
  const float* Ag  = A + (size_t)(bm + ar) * K + kbase + ac;
  const float* Ag2 = TA2 ? (Ab + (size_t)(bm + ar) * K + kbase + ac) : nullptr;
  const float* Bg = B + (size_t)(kbase + bkq) * N + bn + bc;

  float a_reg[16];
  float b_reg[8];

  for (int k0 = 0; k0 < Kc; k0 += 32) {
#pragma unroll
    for (int e = 0; e < 4; e++) {
      float4 v = *(const float4*)(Ag + k0 + 4 * e);
      if constexpr (TA2) {
        float4 w = *(const float4*)(Ag2 + k0 + 4 * e);
        v.x += w.x; v.y += w.y; v.z += w.z; v.w += w.w;
      }
      a_reg[4 * e + 0] = v.x; a_reg[4 * e + 1] = v.y;
      a_reg[4 * e + 2] = v.z; a_reg[4 * e + 3] = v.w;
    }
    {
      const float* Bp = Bg + (size_t)k0 * N;
#pragma unroll
      for (int j = 0; j < 8; j++) b_reg[j] = Bp[(size_t)j * N];
    }
    __syncthreads();
#pragma unroll
    for (int e = 0; e < 2; e++) {
      float4 v0 = {a_reg[8 * e + 0], a_reg[8 * e + 1], a_reg[8 * e + 2], a_reg[8 * e + 3]};
      float4 v1 = {a_reg[8 * e + 4], a_reg[8 * e + 5], a_reg[8 * e + 6], a_reg[8 * e + 7]};
      uint4 hi, lo; split8v(v0, v1, hi, lo);
      *(uint4*)&Ah[ar][ac + 8 * e] = hi;
      *(uint4*)&Al[ar][ac + 8 * e] = lo;
    }
    {
      float4 u0 = {b_reg[0], b_reg[1], b_reg[2], b_reg[3]};
      float4 u1 = {b_reg[4], b_reg[5], b_reg[6], b_reg[7]};
      uint4 hi, lo; split8v(u0, u1, hi, lo);
      *(uint4*)&Bh[bc][bkq] = hi;
      *(uint4*)&Bl[bc][bkq] = lo;
    }
    __syncthreads();

    short8 ah[4], al[4], bh[2], bl[2];
#pragma unroll
    for (int i = 0; i < 4; i++) {
      ah[i] = *(const short8*)&Ah[wm + (i << 4) + fr][fk];
      al[i] = *(const short8*)&Al[wm + (i << 4) + fr][fk];
    }
#pragma unroll
    for (int j = 0; j < 2; j++) {
      bh[j] = *(const short8*)&Bh[wn + (j << 4) + fr][fk];
      bl[j] = *(const short8*)&Bl[wn + (j << 4) + fr][fk];
    }
#pragma unroll
    for (int i = 0; i < 4; i++)
#pragma unroll
      for (int j = 0; j < 2; j++) {
        acc[i][j] = __builtin_amdgcn_mfma_f32_16x16x32_bf16(ah[i], bh[j], acc[i][j], 0, 0, 0);
        acc[i][j] = __builtin_amdgcn_mfma_f32_16x16x32_bf16(ah[i], bl[j], acc[i][j], 0, 0, 0);
        acc[i][j] = __builtin_amdgcn_mfma_f32_16x16x32_bf16(al[i], bh[j], acc[i][j], 0, 0, 0);
      }
  }

  const int cr = (lane >> 4) << 2, cc = lane & 15;
  if constexpr (SPLITK > 1) {
    float* Cp = C + (size_t)z * M * N;
#pragma unroll
    for (int j = 0; j < 2; j++) {
      const int col = bn + wn + (j << 4) + cc;
#pragma unroll
      for (int i = 0; i < 4; i++) {
        const int row0 = bm + wm + (i << 4) + cr;
#pragma unroll
        for (int r = 0; r < 4; r++)
          Cp[(size_t)(row0 + r) * N + col] = acc[i][j][r];
      }
    }
  } else {
#pragma unroll
    for (int j = 0; j < 2; j++) {
      const int col = bn + wn + (j << 4) + cc;
      const float bv = bias[col];
#pragma unroll
      for (int i = 0; i < 4; i++) {
        const int row0 = bm + wm + (i << 4) + cr;
#pragma unroll
        for (int r = 0; r < 4; r++) {
          float v = acc[i][j][r] + bv;
          if constexpr (RES) v += res[(size_t)(row0 + r) * N + col];
          if constexpr (RELU) v = fmaxf(v, 0.f);
          C[(size_t)(row0 + r) * N + col] = v;
        }
      }
    }
  }
}

// ------------------------------------------------------------- combineN (split-K merge + epilogue; r14-proven)
template<int NP, bool HASB, bool RES, bool RELU>
__global__ __launch_bounds__(256)
void combineN_kernel(const float* __restrict__ parts, size_t pstride,
                     const float* __restrict__ bias, const float* __restrict__ res,
                     float* __restrict__ C, int N) {
  const int i = (blockIdx.x * 256 + threadIdx.x) << 2;
  float4 r = *(const float4*)&parts[i];
#pragma unroll
  for (int zz = 1; zz < NP; zz++) {
    float4 a = *(const float4*)&parts[(size_t)zz * pstride + i];
    r.x += a.x; r.y += a.y; r.z += a.z; r.w += a.w;
  }
  if constexpr (HASB) {
    const int col = i % N;
    float4 bv = *(const float4*)&bias[col];
    r.x += bv.x; r.y += bv.y; r.z += bv.z; r.w += bv.w;
  }
  if constexpr (RES) {
    float4 rv = *(const float4*)&res[i];
    r.x += rv.x; r.y += rv.y; r.z += rv.z; r.w += rv.w;
  }
  if constexpr (RELU) {
    r.x = fmaxf(r.x, 0.f); r.y = fmaxf(r.y, 0.f);
    r.z = fmaxf(r.z, 0.f); r.w = fmaxf(r.w, 0.f);
  }
  *(float4*)&C[i] = r;
}

// ------------------------------------------------------------- scores (causal tiles, fused col-chunk stats; r13)
__global__ __launch_bounds__(256)
void scores_kernel(const float* __restrict__ qkv, float* __restrict__ scores,
                   float* __restrict__ pstats) {
  __shared__ short Qh[128][40], Ql[128][40], Kh[128][40], Kl[128][40];
  const int tid = threadIdx.x;
  const int lane = tid & 63, wave = tid >> 6;

  const int lid = xcd_chunk_id(NH * 36);
  const int h = lid / 36;
  int t = lid - h * 36;
  int rr = 0;
  while ((rr + 1) * (rr + 2) / 2 <= t) rr++;   // triangular row
  const int bi = rr << 7;
  const int bj = (t - rr * (rr + 1) / 2) << 7;

  const int wm = (wave >> 1) << 6, wn = (wave & 1) << 6;
  const int fr = lane & 15, fk = (lane >> 4) << 3;
  const float* Q = qkv + h * HD;
  const float* Kp = qkv + D_MODEL + h * HD;

  floatx4 acc[4][4];
#pragma unroll
  for (int i = 0; i < 4; i++)
#pragma unroll
    for (int j = 0; j < 4; j++) acc[i][j] = (floatx4){0.f, 0.f, 0.f, 0.f};

  const int ar = tid >> 1;
  const int ac = (tid & 1) << 4;

  for (int k0 = 0; k0 < HD; k0 += 32) {
    __syncthreads();
    {
      const float* Qp = Q + (size_t)(bi + ar) * D3 + k0 + ac;
#pragma unroll
      for (int e = 0; e < 2; e++) {
        float4 v0 = *(const float4*)(Qp + 8 * e);
        float4 v1 = *(const float4*)(Qp + 8 * e + 4);
        uint4 hi, lo; split8v(v0, v1, hi, lo);
        *(uint4*)&Qh[ar][ac + 8 * e] = hi;
        *(uint4*)&Ql[ar][ac + 8 * e] = lo;
      }
      const float* Kpp = Kp + (size_t)(bj + ar) * D3 + k0 + ac;
#pragma unroll
      for (int e = 0; e < 2; e++) {
        float4 v0 = *(const float4*)(Kpp + 8 * e);
        float4 v1 = *(const float4*)(Kpp + 8 * e + 4);
        uint4 hi, lo; split8v(v0, v1, hi, lo);
        *(uint4*)&Kh[ar][ac + 8 * e] = hi;
        *(uint4*)&Kl[ar][ac + 8 * e] = lo;
      }
    }
    __syncthreads();
    short8 qh[4], ql[4], kh[4], kl[4];
#pragma unroll
    for (int i = 0; i < 4; i++) {
      qh[i] = *(const short8*)&Qh[wm + (i << 4) + fr][fk];
      ql[i] = *(const short8*)&Ql[wm + (i << 4) + fr][fk];
      kh[i] = *(const short8*)&Kh[wn + (i << 4) + fr][fk];
      kl[i] = *(const short8*)&Kl[wn + (i << 4) + fr][fk];
    }
#pragma unroll
    for (int i = 0; i < 4; i++)
#pragma unroll
      for (int j = 0; j < 4; j++) {
        acc[i][j] = __builtin_amdgcn_mfma_f32_16x16x32_bf16(qh[i], kh[j], acc[i][j], 0, 0, 0);
        acc[i][j] = __builtin_amdgcn_mfma_f32_16x16x32_bf16(qh[i], kl[j], acc[i][j], 0, 0, 0);
        acc[i][j] = __builtin_amdgcn_mfma_f32_16x16x32_bf16(ql[i], kh[j], acc[i][j], 0, 0, 0);
        acc[i][j] = __builtin_amdgcn_mfma_f32_16x16x32_bf16(ql[i], kl[j], acc[i][j], 0, 0, 0);
      }
  }

  const int cr = (lane >> 4) << 2, cc = lane & 15;
  float* S = scores + (size_t)h * SEQ * SEQ;
  const int qc = (bi >> 6) + (wave >> 1);   // 64-row chunk id (0..15)
  float* Pm = pstats + (size_t)((h * 16 + qc) * 2 + 0) * 1024;
  float* Pz = pstats + (size_t)((h * 16 + qc) * 2 + 1) * 1024;
#pragma unroll
  for (int j = 0; j < 4; j++) {
    const int col = bj + wn + (j << 4) + cc;
    float vv[16];
    float m = -1e30f;
#pragma unroll
    for (int i = 0; i < 4; i++) {
      const int row0 = bi + wm + (i << 4) + cr;
#pragma unroll
      for (int r = 0; r < 4; r++) {
        float v = (col <= row0 + r) ? acc[i][j][r] * SCALE : -1e30f;
        S[(size_t)(row0 + r) * SEQ + col] = v;
        vv[i * 4 + r] = v;
        m = fmaxf(m, v);
      }
    }
    float zz = 0.f;
#pragma unroll
    for (int t2 = 0; t2 < 16; t2++) zz += __expf(vv[t2] - m);
    if (m == -1e30f) zz = 0.f;
#pragma unroll
    for (int off = 16; off <= 32; off <<= 1) {
      float mo = __shfl_xor(m, off, 64);
      float zo = __shfl_xor(zz, off, 64);
      float mn = fmaxf(m, mo);
      zz = zz * __expf(m - mn) + zo * __expf(mo - mn);
      m = mn;
    }
    if ((lane >> 4) == 0) { Pm[col] = m; Pz[col] = zz; }
  }
}

// ------------------------------------------------------------- attn @ V (balanced splitK=2, fused stats; r13)
__global__ __launch_bounds__(256)
void av_kernel(const float* __restrict__ qkv, const float* __restrict__ scores,
               const float* __restrict__ pstats, float* __restrict__ part) {
  __shared__ short Ph[64][40], Pl[64][40], Vh[128][40], Vl[128][40];
  __shared__ float Ms[512], Rs[512];
  const int tid = threadIdx.x;
  const int lane = tid & 63, wave = tid >> 6;

  const int lid = xcd_chunk_id(NH * 32);     // h*32 + y*2 + z
  const int h = lid >> 5;
  const int t = lid & 31;
  const int y = t >> 1, z = t & 1;
  const int bm = y << 6;

  const int wm = (wave >> 1) << 5, wn = (wave & 1) << 6;
  const int fr = lane & 15, fk = (lane >> 4) << 3;
  const float* S = scores + (size_t)h * SEQ * SEQ;
  const float* V = qkv + 2 * D_MODEL + h * HD;

  const int kbeg = z * (y + 1) * 32;
  const int kend = (z + 1) * (y + 1) * 32;
  const int ncols = kend - kbeg;

  for (int c0 = tid; c0 < ncols; c0 += 256) {
    const int c = kbeg + c0;
    const int q0 = c >> 6;
    float m = -1e30f;
    for (int qc = q0; qc < 16; qc++)
      m = fmaxf(m, pstats[(size_t)((h * 16 + qc) * 2 + 0) * 1024 + c]);
    float zz = 0.f;
    for (int qc = q0; qc < 16; qc++) {
      float pm = pstats[(size_t)((h * 16 + qc) * 2 + 0) * 1024 + c];
      float pz = pstats[(size_t)((h * 16 + qc) * 2 + 1) * 1024 + c];
      zz += pz * __expf(pm - m);
    }
    Ms[c0] = m;
    Rs[c0] = 1.f / zz;
  }

  floatx4 acc[2][4];
#pragma unroll
  for (int i = 0; i < 2; i++)
#pragma unroll
    for (int j = 0; j < 4; j++) acc[i][j] = (floatx4){0.f, 0.f, 0.f, 0.f};

  const int ar = tid >> 2;
  const int ac = (tid & 3) << 3;
  const int bc = tid & 127;
  const int bkq = (tid >> 7) << 4;

  for (int k0 = kbeg; k0 < kend; k0 += 32) {
    __syncthreads();
    {
      const float* Sp = S + (size_t)(bm + ar) * SEQ + k0 + ac;
      float4 v0 = *(const float4*)(Sp);
      float4 v1 = *(const float4*)(Sp + 4);
      float t8[8] = {v0.x, v0.y, v0.z, v0.w, v1.x, v1.y, v1.z, v1.w};
      float4 p0, p1;
      {
        int kk = k0 - kbeg + ac;
        p0.x = __expf(t8[0] - Ms[kk + 0]) * Rs[kk + 0];
        p0.y = __expf(t8[1] - Ms[kk + 1]) * Rs[kk + 1];
        p0.z = __expf(t8[2] - Ms[kk + 2]) * Rs[kk + 2];
        p0.w = __expf(t8[3] - Ms[kk + 3]) * Rs[kk + 3];
        p1.x = __expf(t8[4] - Ms[kk + 4]) * Rs[kk + 4];
        p1.y = __expf(t8[5] - Ms[kk + 5]) * Rs[kk + 5];
        p1.z = __expf(t8[6] - Ms[kk + 6]) * Rs[kk + 6];
        p1.w = __expf(t8[7] - Ms[kk + 7]) * Rs[kk + 7];
      }
      uint4 hi, lo; split8v(p0, p1, hi, lo);
      *(uint4*)&Ph[ar][ac] = hi;
      *(uint4*)&Pl[ar][ac] = lo;
    }
    {
      const float* Vp = V + (size_t)(k0 + bkq) * D3 + bc;
#pragma unroll
      for (int e = 0; e < 2; e++) {
        float4 u0, u1;
        u0.x = Vp[(size_t)(8 * e + 0) * D3]; u0.y = Vp[(size_t)(8 * e + 1) * D3];
        u0.z = Vp[(size_t)(8 * e + 2) * D3]; u0.w = Vp[(size_t)(8 * e + 3) * D3];
        u1.x = Vp[(size_t)(8 * e + 4) * D3]; u1.y = Vp[(size_t)(8 * e + 5) * D3];
        u1.z = Vp[(size_t)(8 * e + 6) * D3]; u1.w = Vp[(size_t)(8 * e + 7) * D3];
        uint4 hi, lo; split8v(u0, u1, hi, lo);
        *(uint4*)&Vh[bc][bkq + 8 * e] = hi;
        *(uint4*)&Vl[bc][bkq + 8 * e] = lo;
      }
    }
    __syncthreads();
    short8 ph[2], pl[2], vh[4], vl[4];
#pragma unroll
    for (int i = 0; i < 2; i++) {
      ph[i] = *(const short8*)&Ph[wm + (i << 4) + fr][fk];
      pl[i] = *(const short8*)&Pl[wm + (i << 4) + fr][fk];
    }
#pragma unroll
    for (int j = 0; j < 4; j++) {
      vh[j] = *(const short8*)&Vh[wn + (j << 4) + fr][fk];
      vl[j] = *(const short8*)&Vl[wn + (j << 4) + fr][fk];
    }
#pragma unroll
    for (int i = 0; i < 2; i++)
#pragma unroll
      for (int j = 0; j < 4; j++) {
        acc[i][j] = __builtin_amdgcn_mfma_f32_16x16x32_bf16(ph[i], vh[j], acc[i][j], 0, 0, 0);
        acc[i][j] = __builtin_amdgcn_mfma_f32_16x16x32_bf16(ph[i], vl[j], acc[i][j], 0, 0, 0);
        acc[i][j] = __builtin_amdgcn_mfma_f32_16x16x32_bf16(pl[i], vh[j], acc[i][j], 0, 0, 0);
      }
  }

  const int cr = (lane >> 4) << 2, cc = lane & 15;
  float* Cp = part + (size_t)z * SEQ * D_MODEL;
#pragma unroll
  for (int j = 0; j < 4; j++) {
    const int col = h * HD + wn + (j << 4) + cc;
#pragma unroll
    for (int i = 0; i < 2; i++) {
      const int row0 = bm + wm + (i << 4) + cr;
#pragma unroll
      for (int r = 0; r < 4; r++)
        Cp[(size_t)(row0 + r) * D_MODEL + col] = acc[i][j][r];
    }
  }
}

// ------------------------------------------------------------- final LN
__global__ __launch_bounds__(256)
void ln_kernel(const float* __restrict__ x, const float* __restrict__ g,
               const float* __restrict__ bb, float* __restrict__ y) {
  __shared__ float red[8];
  const int row = blockIdx.x;
  const float* xr = x + (size_t)row * D_MODEL;
  float v[6];
  float s = 0.f, sq = 0.f;
#pragma unroll
  for (int i = 0; i < 6; i++) {
    v[i] = xr[256 * i + threadIdx.x];
    s += v[i];
    sq += v[i] * v[i];
  }
#pragma unroll
  for (int off = 32; off >= 1; off >>= 1) {
    s += __shfl_down(s, off, 64);
    sq += __shfl_down(sq, off, 64);
  }
  const int lane = threadIdx.x & 63, w = threadIdx.x >> 6;
  if (lane == 0) { red[w] = s; red[4 + w] = sq; }
  __syncthreads();
  if (threadIdx.x == 0) {
    red[0] = red[0] + red[1] + red[2] + red[3];
    red[4] = red[4] + red[5] + red[6] + red[7];
  }
  __syncthreads();
  const float mu = red[0] * (1.f / D_MODEL);
  const float var = red[4] * (1.f / D_MODEL) - mu * mu;
  const float rs = rsqrtf(var + 1e-5f);
#pragma unroll
  for (int i = 0; i < 6; i++) {
    int c = 256 * i + threadIdx.x;
    y[(size_t)row * D_MODEL + c] = (v[i] - mu) * rs * g[c] + bb[c];
  }
}

// ------------------------------------------------------------- launcher
extern "C" void kernel_launch(void* const* d_in, const int* in_sizes, int n_in,
                              void* d_out, int out_size, void* d_ws, size_t ws_size,
                              hipStream_t stream) {
  (void)in_sizes; (void)n_in; (void)out_size; (void)ws_size;
  const int*   idx     = (const int*)d_in[0];
  const float* tok_emb = (const float*)d_in[2];
  const float* pos_emb = (const float*)d_in[3];
  const float* Wqkv    = (const float*)d_in[4];
  const float* bqkv    = (const float*)d_in[5];
  const float* Wo      = (const float*)d_in[6];
  const float* bo      = (const float*)d_in[7];
  const float* W1      = (const float*)d_in[8];
  const float* b1      = (const float*)d_in[9];
  const float* W2      = (const float*)d_in[10];
  const float* b2      = (const float*)d_in[11];
  const float* ln_g    = (const float*)d_in[12];
  const float* ln_b    = (const float*)d_in[13];
  const float* Wout    = (const float*)d_in[14];
  const float* bout    = (const float*)d_in[15];
  float* out = (float*)d_out;

  char* ws = (char*)d_ws;
  float* x      = (float*)(ws);                 //  6.29 MB
  float* qkv    = (float*)(ws + 6291456);       // 18.87 MB
  float* pstats = (float*)(ws + 25165824);      //  1.57 MB
  float* part   = (float*)(ws + 26836992);      // 37.75 MB (6 planes of SEQ*D_MODEL)
  float* U      = (float*)(ws + 64585728);      // 50.33 MB union {scores|h1|xn}
  float* scores = U;
  float* h1     = U;
  float* xn     = U;
  const size_t PN = (size_t)SEQ * D_MODEL;

  embed_kernel<<<6144, 256, 0, stream>>>(idx, tok_emb, pos_emb, x);

  for (int l = 0; l < NL; l++) {
    const float* wqkv = Wqkv + (size_t)l * D_MODEL * D3;
    const float* bq   = bqkv + (size_t)l * D3;
    const float* wo   = Wo   + (size_t)l * D_MODEL * D_MODEL;
    const float* bo_  = bo   + (size_t)l * D_MODEL;
    const float* w1   = W1   + (size_t)l * D_MODEL * D4;
    const float* b1_  = b1   + (size_t)l * D4;
    const float* w2   = W2   + (size_t)l * D4 * D_MODEL;
    const float* b2_  = b2   + (size_t)l * D_MODEL;

    // qkv = x @ Wqkv + bq   (576 blocks)
    mgemm_kernel<false, false, 1, false><<<576, 256, 0, stream>>>(
        x, nullptr, wqkv, bq, nullptr, qkv, SEQ, D3, D_MODEL, 72, 8);
    // attention
    scores_kernel<<<432, 256, 0, stream>>>(qkv, scores, pstats);
    av_kernel<<<384, 256, 0, stream>>>(qkv, scores, pstats, part);   // planes 0,1
    // proj: (av0+av1) @ Wo, splitK=4 -> 768 blocks, planes 2..5
    mgemm_kernel<false, false, 4, true><<<768, 256, 0, stream>>>(
        part, part + PN, wo, nullptr, nullptr, part + 2 * PN,
        SEQ, D_MODEL, D_MODEL, 24, 8);
    combineN_kernel<4, true, true, false><<<1536, 256, 0, stream>>>(
        part + 2 * PN, PN, bo_, x, x, D_MODEL);
    // h1 = relu(x @ W1 + b1)   (768 blocks)
    mgemm_kernel<true, false, 1, false><<<768, 256, 0, stream>>>(
        x, nullptr, w1, b1_, nullptr, h1, SEQ, D4, D_MODEL, 96, 8);
    // ffn2: h1 @ W2, splitK=4 -> 768 blocks, planes 0..3
    mgemm_kernel<false, false, 4, false><<<768, 256, 0, stream>>>(
        h1, nullptr, w2, nullptr, nullptr, part, SEQ, D_MODEL, D4, 24, 8);
    combineN_kernel<4, true, true, false><<<1536, 256, 0, stream>>>(
        part, PN, b2_, x, x, D_MODEL);
  }

  ln_kernel<<<SEQ, 256, 0, stream>>>(x, ln_g, ln_b, xn);
  mgemm_kernel<false, false, 4, false><<<768, 256, 0, stream>>>(
      xn, nullptr, Wout, nullptr, nullptr, part, SEQ, D_MODEL, D_MODEL, 24, 8);
  combineN_kernel<4, true, false, false><<<1536, 256, 0, stream>>>(
      part, PN, bout, nullptr, out, D_MODEL);
}